// Round 5
// baseline (155.194 us; speedup 1.0000x reference)
//
#include <hip/hip_runtime.h>
#include <hip/hip_bf16.h>
#include <cstdio>
#include <cstdint>

// Problem constants (B=2, S=4096, D=1024, E=8, K=2)
static constexpr int TOK = 8192;    // B*S tokens
static constexpr int DIM = 1024;    // model dim (in = out)
static constexpr int NEXP = 8;
static constexpr int NGRP = 16;     // (k, expert) groups
static constexpr int ROWS = TOK * 2;  // 16384 gathered rows

typedef unsigned short u16;
typedef unsigned int u32;

using floatx4 = __attribute__((ext_vector_type(4))) float;
using bf16x8  = __attribute__((ext_vector_type(8))) __bf16;

// meta (ints): [0..15] counts, [16..31] offsets, [48] numTiles
// tileMap: up to 144 ints, (g<<12)|m0

// ---------- helpers ----------
__device__ __forceinline__ u16 f2bf(float f) {
  union { float f; u32 u; } v; v.f = f;
  u32 r = v.u + 0x7fffu + ((v.u >> 16) & 1u);   // RNE
  return (u16)(r >> 16);
}

__device__ __forceinline__ void gload_lds16(const void* g, void* l) {
  __builtin_amdgcn_global_load_lds(
      (const __attribute__((address_space(1))) void*)g,
      (__attribute__((address_space(3))) void*)l,
      16, 0, 0);
}

// ---------- fused bookkeeping (one block, parallel scan/fill) ----------
__global__ __launch_bounds__(1024)
void prep_kernel(const int* __restrict__ idx, const float* __restrict__ ew,
                 int* __restrict__ meta, int* __restrict__ tileMap,
                 int* __restrict__ tokList, float* __restrict__ wList,
                 int* __restrict__ posOf) {
  __shared__ int cnt[NGRP], offS[NGRP], cur[NGRP], tbase[NGRP];
  const int tid = threadIdx.x;            // 1024 threads, 16 items each
  if (tid < NGRP) cnt[tid] = 0;
  __syncthreads();
  int gl[16];
#pragma unroll
  for (int j = 0; j < 16; ++j) {
    int i = tid + 1024 * j;               // (token,k) flat: k = i&1
    int g = ((i & 1) << 3) | idx[i];
    gl[j] = g;
    atomicAdd(&cnt[g], 1);
  }
  __syncthreads();
  if (tid == 0) {                         // tiny 16-step scan
    int run = 0, t = 0;
    for (int g = 0; g < NGRP; ++g) {
      offS[g] = run; cur[g] = run; tbase[g] = t;
      t += (cnt[g] + 127) >> 7;
      run += cnt[g];
    }
    meta[48] = t;
  }
  __syncthreads();
  if (tid < NGRP) {                       // parallel meta + tileMap fill
    meta[tid] = cnt[tid];
    meta[16 + tid] = offS[tid];
    int b = tbase[tid], n = (cnt[tid] + 127) >> 7;
    for (int m0 = 0; m0 < n; ++m0) tileMap[b + m0] = (tid << 12) | m0;
  }
#pragma unroll
  for (int j = 0; j < 16; ++j) {
    int i = tid + 1024 * j;
    int pos = atomicAdd(&cur[gl[j]], 1);
    tokList[pos] = i >> 1;
    wList[pos] = ew[i];
    posOf[i] = pos;
  }
}

// ---------- gather + convert: read each token row ONCE, write its 2 slots ----------
__global__ __launch_bounds__(256)
void gather_x_kernel(const float* __restrict__ x, const int* __restrict__ posOf,
                     u16* __restrict__ Abuf) {
  const int t = blockIdx.x, tid = threadIdx.x;
  float4 v = reinterpret_cast<const float4*>(x + ((size_t)t << 10))[tid];
  ushort4 o;
  o.x = f2bf(v.x); o.y = f2bf(v.y); o.z = f2bf(v.z); o.w = f2bf(v.w);
  const int p0 = posOf[2 * t], p1 = posOf[2 * t + 1];
  reinterpret_cast<ushort4*>(Abuf + ((size_t)p0 << 10))[tid] = o;
  reinterpret_cast<ushort4*>(Abuf + ((size_t)p1 << 10))[tid] = o;
}

// W[e][d][f] fp32 -> Wt[e][f][d] bf16 (LDS-tiled transpose)
__global__ void transpose_w_kernel(const float* __restrict__ W, u16* __restrict__ wt) {
  __shared__ u16 tile[32][33];
  const int e = blockIdx.z;
  const int f0 = blockIdx.x * 32, d0 = blockIdx.y * 32;
  const float* src = W + ((size_t)e << 20);
  u16* dst = wt + ((size_t)e << 20);
  const int tx = threadIdx.x, ty = threadIdx.y;   // 32 x 8
#pragma unroll
  for (int j = 0; j < 4; ++j) {
    int d = d0 + ty + 8 * j;
    tile[ty + 8 * j][tx] = f2bf(src[(size_t)d * DIM + f0 + tx]);
  }
  __syncthreads();
#pragma unroll
  for (int j = 0; j < 4; ++j) {
    int f = f0 + ty + 8 * j;
    dst[(size_t)f * DIM + d0 + tx] = tile[tx][ty + 8 * j];
  }
}

// out = 0 (required: both GEMM passes accumulate via atomics)
__global__ __launch_bounds__(256)
void zero_out_kernel(float4* __restrict__ out) {
  const int i = blockIdx.x * 256 + threadIdx.x;   // grid 2048 -> 2,097,152 float4
#pragma unroll
  for (int j = 0; j < 4; ++j)
    out[i + j * 524288] = (float4){0.f, 0.f, 0.f, 0.f};
}

// ---------- fused grouped GEMM, 128x128x64, single dispatch over 16 groups ----------
// Every group accumulates into zero-initialized out via HW fp32 atomics.
// Each element receives exactly 2 adds (k=0,k=1); fp32 add is commutative ->
// bitwise-deterministic regardless of dispatch/replay order.
__global__ __launch_bounds__(256)
void moe_gemm_kernel(const u16* __restrict__ Abuf, const u16* __restrict__ wt,
                     const float* __restrict__ bias, const int* __restrict__ tokList,
                     const float* __restrict__ wList, const int* __restrict__ meta,
                     const int* __restrict__ tileMap, float* __restrict__ out) {
  constexpr int BM = 128, BN = 128, BK = 64;
  // XCD mapping: nt == XCD id -> per-XCD B working set = 2 MB (L2-resident)
  const int chunk = gridDim.y;
  int lin = blockIdx.y * 8 + blockIdx.x;
  int swz = (lin & 7) * chunk + (lin >> 3);
  int tileIdx = swz >> 3, nt = swz & 7;
  if (tileIdx >= meta[48]) return;

  const int tm = tileMap[tileIdx];
  const int g = tm >> 12, m0 = tm & 0xfff;
  const int e = g & (NEXP - 1);
  const int nrem = meta[g] - m0 * BM;          // rows remaining in group (>0)
  const int listBase = meta[16 + g] + m0 * BM;

  __shared__ __align__(16) u16 As[BM * BK];    // 16KB
  __shared__ __align__(16) u16 Bs[BN * BK];    // 16KB

  const int tid = threadIdx.x;
  const int rowA = tid >> 3;    // 0..31 (stride 32 over 4 rounds)
  const int chnk = tid & 7;     // 16B chunk in a 128B row
  const u16* wb = wt + ((size_t)e << 20);
  const u16* ab = Abuf + ((size_t)listBase << 10);   // contiguous sorted rows

  const int wid = tid >> 6, lane = tid & 63;
  const int wm = (wid >> 1) * 64, wn = (wid & 1) * 64;   // 2x2 waves, 64x64 each
  const int lr = lane & 15, lg = lane >> 4;

  floatx4 acc[4][4];
#pragma unroll
  for (int i = 0; i < 4; ++i)
#pragma unroll
    for (int j = 0; j < 4; ++j) acc[i][j] = (floatx4){0.f, 0.f, 0.f, 0.f};

  for (int kt = 0; kt < DIM / BK; ++kt) {
    __syncthreads();                      // previous tile fully consumed
#pragma unroll
    for (int r = 0; r < 4; ++r) {         // A: contiguous rows of Abuf
      const int row = rowA + 32 * r;
      gload_lds16(ab + ((size_t)row << 10) + kt * BK + chnk * 8,
                  &As[row * BK + chnk * 8]);
    }
#pragma unroll
    for (int r = 0; r < 4; ++r) {         // B: Wt rows (f-major, d-contiguous)
      const int row = rowA + 32 * r;
      gload_lds16(wb + ((size_t)(nt * BN + row) << 10) + kt * BK + chnk * 8,
                  &Bs[row * BK + chnk * 8]);
    }
    asm volatile("s_waitcnt vmcnt(0)" ::: "memory");
    __syncthreads();

#pragma unroll
    for (int ks = 0; ks < 2; ++ks) {      // two K=32 sub-steps
      bf16x8 av[4], bv[4];
#pragma unroll
      for (int mi = 0; mi < 4; ++mi)
        av[mi] = *reinterpret_cast<const bf16x8*>(&As[(wm + mi * 16 + lr) * BK + ks * 32 + lg * 8]);
#pragma unroll
      for (int ni = 0; ni < 4; ++ni)
        bv[ni] = *reinterpret_cast<const bf16x8*>(&Bs[(wn + ni * 16 + lr) * BK + ks * 32 + lg * 8]);
#pragma unroll
      for (int mi = 0; mi < 4; ++mi)
#pragma unroll
        for (int ni = 0; ni < 4; ++ni)
          acc[mi][ni] = __builtin_amdgcn_mfma_f32_16x16x32_bf16(av[mi], bv[ni], acc[mi][ni], 0, 0, 0);
    }
  }

  // epilogue: D[row=(lane>>4)*4+r][col=lane&15] per 16x16 frag; atomic accumulate
  const float* bp = bias + e * DIM;
#pragma unroll
  for (int mi = 0; mi < 4; ++mi) {
#pragma unroll
    for (int r = 0; r < 4; ++r) {
      const int rl = wm + mi * 16 + lg * 4 + r;
      if (rl < nrem) {
        const int   tok = tokList[listBase + rl];
        const float w   = wList[listBase + rl];
        float* orow = out + ((size_t)tok << 10);
#pragma unroll
        for (int ni = 0; ni < 4; ++ni) {
          const int col = nt * BN + wn + ni * 16 + lr;
          unsafeAtomicAdd(&orow[col], w * (acc[mi][ni][r] + bp[col]));
        }
      }
    }
  }
}

// ---------- host ----------
extern "C" void kernel_launch(void* const* d_in, const int* in_sizes, int n_in,
                              void* d_out, int out_size, void* d_ws, size_t ws_size,
                              hipStream_t stream) {
  const float* x    = (const float*)d_in[0];   // [2,4096,1024] f32
  const float* ew   = (const float*)d_in[1];   // [2,4096,2]    f32
  const int*   idx  = (const int*)d_in[2];     // [2,4096,2]    i32
  const float* W    = (const float*)d_in[3];   // [8,1024,1024] f32
  const float* bias = (const float*)d_in[4];   // [8,1024]      f32
  float* out = (float*)d_out;                  // [2,4096,1024] f32

  char* ws = (char*)d_ws;
  u16*   Abuf = (u16*)ws;                                  // 32 MB sorted bf16 rows
  u16*   wtp  = (u16*)(ws + ((size_t)32 << 20));           // 16 MB bf16 W^T
  char*  tail = ws + ((size_t)48 << 20);
  int*   tokList = (int*)tail;                  // 64 KB
  float* wList   = (float*)(tail + (64 << 10)); // 64 KB
  int*   posOf   = (int*)(tail + (128 << 10));  // 64 KB
  int*   meta    = (int*)(tail + (192 << 10));  // 64 ints
  int*   tileMap = (int*)(tail + (193 << 10));  // 144 ints

  const size_t need = ((size_t)48 << 20) + (194 << 10);
  if (ws_size < need) {
    fprintf(stderr, "kernel_launch: ws_size %zu < needed %zu\n", ws_size, need);
    return;
  }

  zero_out_kernel<<<2048, 256, 0, stream>>>((float4*)out);
  prep_kernel<<<1, 1024, 0, stream>>>(idx, ew, meta, tileMap, tokList, wList, posOf);
  gather_x_kernel<<<TOK, 256, 0, stream>>>(x, posOf, Abuf);
  transpose_w_kernel<<<dim3(32, 32, 8), dim3(32, 8), 0, stream>>>(W, wtp);
  moe_gemm_kernel<<<dim3(8, 144), 256, 0, stream>>>(
      Abuf, wtp, bias, tokList, wList, meta, tileMap, out);
}